// Round 1
// baseline (5856.007 us; speedup 1.0000x reference)
//
#include <hip/hip_runtime.h>
#include <stdint.h>
#include <stddef.h>

typedef __attribute__((ext_vector_type(8))) short short8;
typedef __attribute__((ext_vector_type(4))) float f32x4;

#define DI __device__ __forceinline__

DI short f2bf(float f){
    union { float f; unsigned u; } v; v.f = f;
    unsigned r = (v.u + 0x7FFFu + ((v.u >> 16) & 1u)) >> 16;
    return (short)r;
}
DI float bf2f(short s){
    union { unsigned u; float f; } v;
    v.u = ((unsigned)(unsigned short)s) << 16;
    return v.f;
}

// block reduce over 256 threads (4 waves), returns total to all threads
DI float blockReduceSum(float v, float* red){
    #pragma unroll
    for (int o = 32; o > 0; o >>= 1) v += __shfl_down(v, o);
    __syncthreads();                       // protect red across successive calls
    if ((threadIdx.x & 63) == 0) red[threadIdx.x >> 6] = v;
    __syncthreads();
    return red[0] + red[1] + red[2] + red[3];
}

// ---------------------------------------------------------------------------
// fp32 -> bf16 convert (vectorized)
__global__ void cvt_k(const float* __restrict__ s, short* __restrict__ d, int n){
    int i = (blockIdx.x * 256 + threadIdx.x) * 4;
    if (i >= n) return;
    float4 f = *(const float4*)(s + i);
    short4 o;
    o.x = f2bf(f.x); o.y = f2bf(f.y); o.z = f2bf(f.z); o.w = f2bf(f.w);
    *(short4*)(d + i) = o;
}

__global__ void prep_small_k(const float* __restrict__ bih, const float* __restrict__ bhh,
                             float* __restrict__ bias_comb,
                             const float* __restrict__ bq, const float* __restrict__ bk,
                             const float* __restrict__ bv, float* __restrict__ bqkv){
    int t = blockIdx.x * 256 + threadIdx.x;
    if (t < 4096) bias_comb[t] = bih[t] + bhh[t];
    if (t < 1024){ bqkv[t] = bq[t]; bqkv[1024 + t] = bk[t]; bqkv[2048 + t] = bv[t]; }
}

__global__ void sentinel_k(float* out){ out[768] = -123456.0f; }

// ---------------------------------------------------------------------------
// Generic bf16 GEMM: C[M,N] = A[M,K] @ B[N,K]^T  (+ bias[col])
// mode 0: write bf16 to xp layout [s][b][4096] where row r = b*1024+s
// mode 1: write fp32 to outf[row*N+col]
__global__ __launch_bounds__(256) void gemm_bf16_k(
    const short* __restrict__ A, const short* __restrict__ B,
    int M, int N, int K,
    const float* __restrict__ bias,
    short* __restrict__ outb, float* __restrict__ outf, int mode)
{
    __shared__ short As[128 * 64];
    __shared__ short Bs[128 * 64];
    const int tid  = threadIdx.x;
    const int lane = tid & 63, wv = tid >> 6;
    const int row0 = blockIdx.y * 128, col0 = blockIdx.x * 128;

    f32x4 acc[4][4];
    #pragma unroll
    for (int i = 0; i < 4; ++i)
        #pragma unroll
        for (int j = 0; j < 4; ++j) acc[i][j] = (f32x4){0.f, 0.f, 0.f, 0.f};

    for (int k0 = 0; k0 < K; k0 += 64){
        __syncthreads();
        #pragma unroll
        for (int i = 0; i < 4; ++i){
            int off = i * 4096 + tid * 16;          // byte offset in 16KB tile
            int row = off >> 7, kb = off & 127;     // 128B per row (64 bf16)
            int dst = (row * 128 + (kb ^ ((row & 7) << 4))) >> 1;
            short8 va = *(const short8*)(A + (size_t)(row0 + row) * K + k0 + (kb >> 1));
            *(short8*)&As[dst] = va;
            short8 vb = *(const short8*)(B + (size_t)(col0 + row) * K + k0 + (kb >> 1));
            *(short8*)&Bs[dst] = vb;
        }
        __syncthreads();
        #pragma unroll
        for (int kk = 0; kk < 2; ++kk){
            short8 af[4], bfr[4];
            int kb = kk * 64 + (lane >> 4) * 16;    // byte offset of this lane's 8 k's
            #pragma unroll
            for (int mf = 0; mf < 4; ++mf){
                int row = (wv & 1) * 64 + mf * 16 + (lane & 15);
                af[mf] = *(const short8*)&As[(row * 128 + (kb ^ ((row & 7) << 4))) >> 1];
                int col = (wv >> 1) * 64 + mf * 16 + (lane & 15);
                bfr[mf] = *(const short8*)&Bs[(col * 128 + (kb ^ ((col & 7) << 4))) >> 1];
            }
            #pragma unroll
            for (int mf = 0; mf < 4; ++mf)
                #pragma unroll
                for (int nf = 0; nf < 4; ++nf)
                    acc[mf][nf] = __builtin_amdgcn_mfma_f32_16x16x32_bf16(
                        af[mf], bfr[nf], acc[mf][nf], 0, 0, 0);
        }
    }

    #pragma unroll
    for (int mf = 0; mf < 4; ++mf){
        #pragma unroll
        for (int nf = 0; nf < 4; ++nf){
            #pragma unroll
            for (int r = 0; r < 4; ++r){
                int rl = (wv & 1) * 64 + mf * 16 + (lane >> 4) * 4 + r;
                int cl = (wv >> 1) * 64 + nf * 16 + (lane & 15);
                int rg = row0 + rl, cg = col0 + cl;
                float v = acc[mf][nf][r] + bias[cg];
                if (mode == 0){
                    int s = rg & 1023, b = rg >> 10;
                    outb[((size_t)s * 8 + b) * 4096 + cg] = f2bf(v);
                } else {
                    outf[(size_t)rg * N + cg] = v;
                }
            }
        }
    }
}

// ---------------------------------------------------------------------------
// Persistent LSTM recurrence. 64 WGs x 256 threads. WG wg owns hidden slice
// n in [wg*16, wg*16+16) i.e. 64 gate columns g = gp*1024 + wg*16 + nloc.
// Local col c = nloc*4+gp. Wave wv handles k-quarter [wv*256, wv*256+256).
// w_hh B-fragments persistent in registers (bf16). h broadcast via agent-scope
// atomics in hbuf[2][16][1024] (rows 8..15 stay zero), per-step flags.
__global__ __launch_bounds__(256, 1) void lstm_rec_k(
    const short* __restrict__ xp,    // [1024][8][4096] bf16
    const float* __restrict__ whh,   // [4096][1024] fp32
    float* __restrict__ h_all,       // [1024][8][1024] fp32
    short* hbuf,                     // [2][16][1024] bf16, pre-zeroed
    unsigned* flags)                 // [1024][64], pre-zeroed
{
    const int wg = blockIdx.x;
    const int tid = threadIdx.x;
    const int lane = tid & 63, wv = tid >> 6;
    __shared__ float scratch[4][64][16];   // [wave][localcol][row]

    // ---- persistent w_hh fragments: wfr[nf][kk], k = wv*256 + kk*32 + (lane>>4)*8 + e
    short8 wfr[4][8];
    {
        const int cl = lane & 15, kq = lane >> 4;
        #pragma unroll
        for (int nf = 0; nf < 4; ++nf){
            int c = nf * 16 + cl;
            int g = (c & 3) * 1024 + wg * 16 + (c >> 2);
            const float* wr = whh + (size_t)g * 1024 + wv * 256 + kq * 8;
            #pragma unroll
            for (int kk = 0; kk < 8; ++kk){
                short8 w;
                #pragma unroll
                for (int e = 0; e < 8; ++e) w[e] = f2bf(wr[kk * 32 + e]);
                wfr[nf][kk] = w;
            }
        }
    }

    const int b_a = tid >> 4, nl_a = tid & 15;   // activation mapping (tid<128)
    float c_reg = 0.f;
    unsigned* hb32 = (unsigned*)hbuf;

    for (int t = 0; t < 1024; ++t){
        // xp prefetch (independent of h)
        float xg0 = 0.f, xg1 = 0.f, xg2 = 0.f, xg3 = 0.f;
        if (tid < 128){
            const short* xr = xp + ((size_t)t * 8 + b_a) * 4096 + wg * 16 + nl_a;
            xg0 = bf2f(xr[0]); xg1 = bf2f(xr[1024]); xg2 = bf2f(xr[2048]); xg3 = bf2f(xr[3072]);
        }
        // wait for all WGs to have published h(t-1)
        if (t > 0 && tid < 64){
            unsigned* fl = flags + (size_t)(t - 1) * 64 + lane;
            int guard = 0;
            while (__hip_atomic_load(fl, __ATOMIC_ACQUIRE, __HIP_MEMORY_SCOPE_AGENT) == 0u){
                __builtin_amdgcn_s_sleep(1);
                if (++guard > (1 << 18)) break;   // hang insurance
            }
        }
        __syncthreads();
        __builtin_amdgcn_fence(__ATOMIC_ACQUIRE, "agent");

        // ---- gates partial = h(t-1)[k-quarter wv] @ whh-slice
        const short* ha = hbuf + (((t + 1) & 1) * 16 + (lane & 15)) * 1024
                          + wv * 256 + (lane >> 4) * 8;
        short8 af[8];
        #pragma unroll
        for (int kk = 0; kk < 8; ++kk) af[kk] = *(const short8*)(ha + kk * 32);
        f32x4 a0 = {0.f,0.f,0.f,0.f}, a1 = {0.f,0.f,0.f,0.f};
        f32x4 a2 = {0.f,0.f,0.f,0.f}, a3 = {0.f,0.f,0.f,0.f};
        #pragma unroll
        for (int kk = 0; kk < 8; ++kk){
            a0 = __builtin_amdgcn_mfma_f32_16x16x32_bf16(af[kk], wfr[0][kk], a0, 0, 0, 0);
            a1 = __builtin_amdgcn_mfma_f32_16x16x32_bf16(af[kk], wfr[1][kk], a1, 0, 0, 0);
            a2 = __builtin_amdgcn_mfma_f32_16x16x32_bf16(af[kk], wfr[2][kk], a2, 0, 0, 0);
            a3 = __builtin_amdgcn_mfma_f32_16x16x32_bf16(af[kk], wfr[3][kk], a3, 0, 0, 0);
        }
        {
            int r0 = (lane >> 4) * 4;
            *(f32x4*)&scratch[wv][0 * 16 + (lane & 15)][r0] = a0;
            *(f32x4*)&scratch[wv][1 * 16 + (lane & 15)][r0] = a1;
            *(f32x4*)&scratch[wv][2 * 16 + (lane & 15)][r0] = a2;
            *(f32x4*)&scratch[wv][3 * 16 + (lane & 15)][r0] = a3;
        }
        __syncthreads();

        if (tid < 128){
            int c0 = nl_a * 4;
            float g0 = xg0 + scratch[0][c0+0][b_a] + scratch[1][c0+0][b_a] + scratch[2][c0+0][b_a] + scratch[3][c0+0][b_a];
            float g1 = xg1 + scratch[0][c0+1][b_a] + scratch[1][c0+1][b_a] + scratch[2][c0+1][b_a] + scratch[3][c0+1][b_a];
            float g2 = xg2 + scratch[0][c0+2][b_a] + scratch[1][c0+2][b_a] + scratch[2][c0+2][b_a] + scratch[3][c0+2][b_a];
            float g3 = xg3 + scratch[0][c0+3][b_a] + scratch[1][c0+3][b_a] + scratch[2][c0+3][b_a] + scratch[3][c0+3][b_a];
            float ig = 1.f / (1.f + expf(-g0));
            float fg = 1.f / (1.f + expf(-g1));
            float gg = tanhf(g2);
            float og = 1.f / (1.f + expf(-g3));
            c_reg = fg * c_reg + ig * gg;
            float h = og * tanhf(c_reg);
            h_all[((size_t)t * 8 + b_a) * 1024 + wg * 16 + nl_a] = h;
            unsigned hb = (unsigned)(unsigned short)f2bf(h);
            unsigned oth = (unsigned)__shfl_xor((int)hb, 1);
            if ((tid & 1) == 0){
                unsigned pk = hb | (oth << 16);
                __hip_atomic_store(hb32 + ((size_t)(t & 1) * 16 + b_a) * 512 + wg * 8 + (nl_a >> 1),
                                   pk, __ATOMIC_RELAXED, __HIP_MEMORY_SCOPE_AGENT);
            }
        }
        __syncthreads();   // drains all waves' stores (vmcnt(0) before s_barrier)
        if (tid == 192)    // wave 3 publishes; wave 0 is the poller (no self-dependence)
            __hip_atomic_store(flags + (size_t)t * 64 + wg, 1u,
                               __ATOMIC_RELAXED, __HIP_MEMORY_SCOPE_AGENT);
    }
}

// ---------------------------------------------------------------------------
// span-mean pooling + LayerNorm -> fv (fp32 + bf16)
__global__ __launch_bounds__(256) void pool_ln_k(
    const float* __restrict__ h_all,
    const int* __restrict__ heads, const int* __restrict__ tails,
    const float* __restrict__ lng, const float* __restrict__ lnb,
    float* __restrict__ fv, short* __restrict__ fvb)
{
    const int R = blockIdx.x;           // b*32+j
    const int b = R >> 5;
    const int tid = threadIdx.x;
    __shared__ float red[8];
    int head = heads[R], tail = tails[R];
    float s[4] = {0.f, 0.f, 0.f, 0.f};
    int cnt = 0;
    for (int t = head + 1; t < tail; ++t){
        const float* hp = h_all + ((size_t)t * 8 + b) * 1024;
        #pragma unroll
        for (int i = 0; i < 4; ++i) s[i] += hp[tid + i * 256];
        ++cnt;
    }
    float inv = 1.f / (float)cnt;
    #pragma unroll
    for (int i = 0; i < 4; ++i) s[i] *= inv;
    float mu = blockReduceSum(s[0] + s[1] + s[2] + s[3], red) * (1.f / 1024.f);
    float d2 = 0.f;
    #pragma unroll
    for (int i = 0; i < 4; ++i){ float d = s[i] - mu; d2 += d * d; }
    float var = blockReduceSum(d2, red) * (1.f / 1024.f);
    float rstd = 1.f / sqrtf(var + 1e-7f);
    #pragma unroll
    for (int i = 0; i < 4; ++i){
        int n = tid + i * 256;
        float y = (s[i] - mu) * rstd * lng[n] + lnb[n];
        fv[(size_t)R * 1024 + n] = y;
        fvb[(size_t)R * 1024 + n] = f2bf(y);
    }
}

// ---------------------------------------------------------------------------
// attention per (b, head): qkv [256][3072] fp32 -> ctx_bf16 [256][1024]
__global__ __launch_bounds__(256) void attn_k(
    const float* __restrict__ qkv, const int* __restrict__ amask,
    short* __restrict__ ctxb)
{
    const int b = blockIdx.x >> 4, hh = blockIdx.x & 15;
    const int tid = threadIdx.x;
    __shared__ float q[32][64], k[32][64], v[32][64], sc[32][32];
    #pragma unroll
    for (int i = 0; i < 8; ++i){
        int e = tid + i * 256;
        int j = e >> 6, dd = e & 63;
        const float* base = qkv + (size_t)(b * 32 + j) * 3072 + hh * 64 + dd;
        q[j][dd] = base[0];
        k[j][dd] = base[1024];
        v[j][dd] = base[2048];
    }
    __syncthreads();
    #pragma unroll
    for (int i = 0; i < 4; ++i){
        int e = tid + i * 256;
        int qj = e >> 5, kj = e & 31;
        float d = 0.f;
        #pragma unroll
        for (int x = 0; x < 64; ++x) d += q[qj][x] * k[kj][x];
        bool ok = (amask[b * 32 + qj] * amask[b * 32 + kj]) > 0;
        sc[qj][kj] = ok ? d * 0.125f : -3.402823466e38f;
    }
    __syncthreads();
    if (tid < 32){
        float mx = -3.402823466e38f;
        #pragma unroll
        for (int kj = 0; kj < 32; ++kj) mx = fmaxf(mx, sc[tid][kj]);
        float sum = 0.f;
        #pragma unroll
        for (int kj = 0; kj < 32; ++kj){
            float ev = expf(sc[tid][kj] - mx);
            sc[tid][kj] = ev; sum += ev;
        }
        float inv = 1.f / sum;
        int mq = amask[b * 32 + tid];
        #pragma unroll
        for (int kj = 0; kj < 32; ++kj){
            bool ok = (mq * amask[b * 32 + kj]) > 0;
            sc[tid][kj] = ok ? sc[tid][kj] * inv : 0.f;
        }
    }
    __syncthreads();
    #pragma unroll
    for (int i = 0; i < 8; ++i){
        int e = tid + i * 256;
        int qj = e >> 6, dd = e & 63;
        float s = 0.f;
        #pragma unroll
        for (int kj = 0; kj < 32; ++kj) s += sc[qj][kj] * v[kj][dd];
        ctxb[(size_t)(b * 32 + qj) * 1024 + hh * 64 + dd] = f2bf(s);
    }
}

// ---------------------------------------------------------------------------
// LN2(oproj + fv) then logits = fv2 @ cls_w^T + cls_b  -> d_out[0..768)
__global__ __launch_bounds__(256) void ln2_logits_k(
    const float* __restrict__ oproj, const float* __restrict__ fv,
    const float* __restrict__ g2, const float* __restrict__ b2,
    const float* __restrict__ clsw, const float* __restrict__ clsb,
    float* __restrict__ out)
{
    const int R = blockIdx.x, tid = threadIdx.x;
    __shared__ float red[8];
    float x[4];
    #pragma unroll
    for (int i = 0; i < 4; ++i){
        int n = tid + i * 256;
        x[i] = oproj[(size_t)R * 1024 + n] + fv[(size_t)R * 1024 + n];
    }
    float mu = blockReduceSum(x[0] + x[1] + x[2] + x[3], red) * (1.f / 1024.f);
    float d2 = 0.f;
    #pragma unroll
    for (int i = 0; i < 4; ++i){ float d = x[i] - mu; d2 += d * d; }
    float var = blockReduceSum(d2, red) * (1.f / 1024.f);
    float rstd = 1.f / sqrtf(var + 1e-7f);
    float y[4];
    #pragma unroll
    for (int i = 0; i < 4; ++i){
        int n = tid + i * 256;
        y[i] = (x[i] - mu) * rstd * g2[n] + b2[n];
    }
    #pragma unroll
    for (int c = 0; c < 3; ++c){
        float p = 0.f;
        #pragma unroll
        for (int i = 0; i < 4; ++i){
            int n = tid + i * 256;
            p += y[i] * clsw[c * 1024 + n];
        }
        float tot = blockReduceSum(p, red);
        if (tid == 0) out[R * 3 + c] = tot + clsb[c];
    }
}

// ---------------------------------------------------------------------------
// CE + focal loss over 256 rows of 3 logits -> d_out[768]
__global__ __launch_bounds__(256) void loss_k(
    const float* __restrict__ logits, const int* __restrict__ labels,
    float* __restrict__ out)
{
    const int tid = threadIdx.x;
    __shared__ float red[8];
    float l0 = logits[tid * 3 + 0], l1 = logits[tid * 3 + 1], l2 = logits[tid * 3 + 2];
    int lab = labels[tid];
    float vf = (lab >= 0) ? 1.f : 0.f;
    int lc = lab < 0 ? 0 : (lab > 2 ? 2 : lab);
    float mx = fmaxf(l0, fmaxf(l1, l2));
    float e0 = expf(l0 - mx), e1 = expf(l1 - mx), e2 = expf(l2 - mx);
    float lse = mx + logf(e0 + e1 + e2);
    float lsel = (lc == 0) ? l0 : ((lc == 1) ? l1 : l2);
    float logp = lsel - lse;
    float pt = expf(logp);
    float om = 1.f - pt;
    float nll = -logp;
    float fnll = -(om * om * om * logp);
    float snll = blockReduceSum(nll * vf, red);
    float sfn  = blockReduceSum(fnll * vf, red);
    float svf  = blockReduceSum(vf, red);
    if (tid == 0) out[768] = (snll + sfn) / svf;
}

// ---------------------------------------------------------------------------
extern "C" void kernel_launch(void* const* d_in, const int* in_sizes, int n_in,
                              void* d_out, int out_size, void* d_ws, size_t ws_size,
                              hipStream_t stream)
{
    const float* hidden = (const float*)d_in[0];
    const int*   sh     = (const int*)d_in[1];
    const int*   st     = (const int*)d_in[2];
    const int*   am     = (const int*)d_in[3];
    const int*   labels = (const int*)d_in[4];
    const float* wih    = (const float*)d_in[5];
    const float* whh    = (const float*)d_in[6];
    const float* bih    = (const float*)d_in[7];
    const float* bhh    = (const float*)d_in[8];
    const float* lng    = (const float*)d_in[9];
    const float* lnb    = (const float*)d_in[10];
    const float* wq     = (const float*)d_in[11];
    const float* bq     = (const float*)d_in[12];
    const float* wk     = (const float*)d_in[13];
    const float* bk     = (const float*)d_in[14];
    const float* wvv    = (const float*)d_in[15];
    const float* bv     = (const float*)d_in[16];
    const float* wo     = (const float*)d_in[17];
    const float* bo     = (const float*)d_in[18];
    const float* g2     = (const float*)d_in[19];
    const float* b2     = (const float*)d_in[20];
    const float* clsw   = (const float*)d_in[21];
    const float* clsb   = (const float*)d_in[22];
    float* out = (float*)d_out;

    const size_t MB = 1u << 20;
    const size_t NEED = 136 * MB;
    if (ws_size < NEED){ sentinel_k<<<1, 1, 0, stream>>>(out); return; }

    char* w = (char*)d_ws;
    short*    xp      = (short*)(w);                       // 64MB [1024][8][4096]
    float*    h_all   = (float*)(w + 64 * MB);             // 32MB [1024][8][1024]
    short*    x_bf    = (short*)(w + 96 * MB);             // 16MB
    short*    wih_bf  = (short*)(w + 112 * MB);            // 8MB
    short*    wqkv_bf = (short*)(w + 120 * MB);            // 6MB
    short*    wo_bf   = (short*)(w + 126 * MB);            // 2MB
    short*    hbuf    = (short*)(w + 128 * MB);            // 64KB
    unsigned* flags   = (unsigned*)(w + 128 * MB + (64u << 10));   // 256KB
    float*    bias_c  = (float*)(w + 128 * MB + (320u << 10));     // 16KB
    float*    bqkv    = (float*)(w + 128 * MB + (336u << 10));     // 12KB
    float*    fv      = (float*)(w + 129 * MB);            // 1MB
    short*    fv_bf   = (short*)(w + 130 * MB);            // 0.5MB
    float*    qkv     = (float*)(w + 131 * MB);            // 3MB
    short*    ctx_bf  = (short*)(w + 134 * MB);            // 0.5MB
    float*    oproj   = (float*)(w + 135 * MB);            // 1MB

    hipMemsetAsync(flags, 0, 1024 * 64 * 4, stream);
    hipMemsetAsync(hbuf, 0, 2 * 16 * 1024 * 2, stream);

    cvt_k<<<8192, 256, 0, stream>>>(hidden, x_bf, 8388608);
    cvt_k<<<4096, 256, 0, stream>>>(wih, wih_bf, 4194304);
    cvt_k<<<1024, 256, 0, stream>>>(wq,  wqkv_bf,           1048576);
    cvt_k<<<1024, 256, 0, stream>>>(wk,  wqkv_bf + 1048576, 1048576);
    cvt_k<<<1024, 256, 0, stream>>>(wvv, wqkv_bf + 2097152, 1048576);
    cvt_k<<<1024, 256, 0, stream>>>(wo,  wo_bf,             1048576);
    prep_small_k<<<16, 256, 0, stream>>>(bih, bhh, bias_c, bq, bk, bv, bqkv);

    // xp = hidden @ w_ih^T + (b_ih + b_hh), stored [s][b][4096] bf16
    gemm_bf16_k<<<dim3(32, 64), 256, 0, stream>>>(x_bf, wih_bf, 8192, 4096, 1024,
                                                  bias_c, xp, nullptr, 0);
    // sequential LSTM
    lstm_rec_k<<<64, 256, 0, stream>>>(xp, whh, h_all, hbuf, flags);
    // span-mean pool + LN1
    pool_ln_k<<<256, 256, 0, stream>>>(h_all, sh, st, lng, lnb, fv, fv_bf);
    // q,k,v projections (concat)
    gemm_bf16_k<<<dim3(24, 2), 256, 0, stream>>>(fv_bf, wqkv_bf, 256, 3072, 1024,
                                                 bqkv, nullptr, qkv, 1);
    // attention
    attn_k<<<128, 256, 0, stream>>>(qkv, am, ctx_bf);
    // output projection (+bo)
    gemm_bf16_k<<<dim3(8, 2), 256, 0, stream>>>(ctx_bf, wo_bf, 256, 1024, 1024,
                                                bo, nullptr, oproj, 1);
    // residual + LN2 + classifier logits
    ln2_logits_k<<<256, 256, 0, stream>>>(oproj, fv, g2, b2, clsw, clsb, out);
    // CE + focal loss
    loss_k<<<1, 256, 0, stream>>>(out, labels, out);
}

// Round 2
// 4540.944 us; speedup vs baseline: 1.2896x; 1.2896x over previous
//
#include <hip/hip_runtime.h>
#include <stdint.h>
#include <stddef.h>

typedef __attribute__((ext_vector_type(8))) short short8;
typedef __attribute__((ext_vector_type(4))) float f32x4;

#define DI __device__ __forceinline__

DI short f2bf(float f){
    union { float f; unsigned u; } v; v.f = f;
    unsigned r = (v.u + 0x7FFFu + ((v.u >> 16) & 1u)) >> 16;
    return (short)r;
}
DI float bf2f(short s){
    union { unsigned u; float f; } v;
    v.u = ((unsigned)(unsigned short)s) << 16;
    return v.f;
}

// block reduce over 256 threads (4 waves), returns total to all threads
DI float blockReduceSum(float v, float* red){
    #pragma unroll
    for (int o = 32; o > 0; o >>= 1) v += __shfl_down(v, o);
    __syncthreads();                       // protect red across successive calls
    if ((threadIdx.x & 63) == 0) red[threadIdx.x >> 6] = v;
    __syncthreads();
    return red[0] + red[1] + red[2] + red[3];
}

// ---------------------------------------------------------------------------
// fp32 -> bf16 convert (vectorized)
__global__ void cvt_k(const float* __restrict__ s, short* __restrict__ d, int n){
    int i = (blockIdx.x * 256 + threadIdx.x) * 4;
    if (i >= n) return;
    float4 f = *(const float4*)(s + i);
    short4 o;
    o.x = f2bf(f.x); o.y = f2bf(f.y); o.z = f2bf(f.z); o.w = f2bf(f.w);
    *(short4*)(d + i) = o;
}

__global__ void prep_small_k(const float* __restrict__ bih, const float* __restrict__ bhh,
                             float* __restrict__ bias_comb,
                             const float* __restrict__ bq, const float* __restrict__ bk,
                             const float* __restrict__ bv, float* __restrict__ bqkv){
    int t = blockIdx.x * 256 + threadIdx.x;
    if (t < 4096) bias_comb[t] = bih[t] + bhh[t];
    if (t < 1024){ bqkv[t] = bq[t]; bqkv[1024 + t] = bk[t]; bqkv[2048 + t] = bv[t]; }
}

__global__ void sentinel_k(float* out){ out[768] = -123456.0f; }

// ---------------------------------------------------------------------------
// Generic bf16 GEMM: C[M,N] = A[M,K] @ B[N,K]^T  (+ bias[col])
// mode 0: write bf16 to xp layout [wg][t][b][64]  (per-LSTM-WG contiguous)
// mode 1: write fp32 to outf[row*N+col]
__global__ __launch_bounds__(256) void gemm_bf16_k(
    const short* __restrict__ A, const short* __restrict__ B,
    int M, int N, int K,
    const float* __restrict__ bias,
    short* __restrict__ outb, float* __restrict__ outf, int mode)
{
    __shared__ short As[128 * 64];
    __shared__ short Bs[128 * 64];
    const int tid  = threadIdx.x;
    const int lane = tid & 63, wv = tid >> 6;
    const int row0 = blockIdx.y * 128, col0 = blockIdx.x * 128;

    f32x4 acc[4][4];
    #pragma unroll
    for (int i = 0; i < 4; ++i)
        #pragma unroll
        for (int j = 0; j < 4; ++j) acc[i][j] = (f32x4){0.f, 0.f, 0.f, 0.f};

    for (int k0 = 0; k0 < K; k0 += 64){
        __syncthreads();
        #pragma unroll
        for (int i = 0; i < 4; ++i){
            int off = i * 4096 + tid * 16;          // byte offset in 16KB tile
            int row = off >> 7, kb = off & 127;     // 128B per row (64 bf16)
            int dst = (row * 128 + (kb ^ ((row & 7) << 4))) >> 1;
            short8 va = *(const short8*)(A + (size_t)(row0 + row) * K + k0 + (kb >> 1));
            *(short8*)&As[dst] = va;
            short8 vb = *(const short8*)(B + (size_t)(col0 + row) * K + k0 + (kb >> 1));
            *(short8*)&Bs[dst] = vb;
        }
        __syncthreads();
        #pragma unroll
        for (int kk = 0; kk < 2; ++kk){
            short8 af[4], bfr[4];
            int kb = kk * 64 + (lane >> 4) * 16;    // byte offset of this lane's 8 k's
            #pragma unroll
            for (int mf = 0; mf < 4; ++mf){
                int row = (wv & 1) * 64 + mf * 16 + (lane & 15);
                af[mf] = *(const short8*)&As[(row * 128 + (kb ^ ((row & 7) << 4))) >> 1];
                int col = (wv >> 1) * 64 + mf * 16 + (lane & 15);
                bfr[mf] = *(const short8*)&Bs[(col * 128 + (kb ^ ((col & 7) << 4))) >> 1];
            }
            #pragma unroll
            for (int mf = 0; mf < 4; ++mf)
                #pragma unroll
                for (int nf = 0; nf < 4; ++nf)
                    acc[mf][nf] = __builtin_amdgcn_mfma_f32_16x16x32_bf16(
                        af[mf], bfr[nf], acc[mf][nf], 0, 0, 0);
        }
    }

    #pragma unroll
    for (int mf = 0; mf < 4; ++mf){
        #pragma unroll
        for (int nf = 0; nf < 4; ++nf){
            #pragma unroll
            for (int r = 0; r < 4; ++r){
                int rl = (wv & 1) * 64 + mf * 16 + (lane >> 4) * 4 + r;
                int cl = (wv >> 1) * 64 + nf * 16 + (lane & 15);
                int rg = row0 + rl, cg = col0 + cl;
                float v = acc[mf][nf][r] + bias[cg];
                if (mode == 0){
                    int s = rg & 1023, b = rg >> 10;       // A row = b*1024 + s
                    int gate = cg >> 10, c1 = cg & 1023;
                    int wgi = c1 >> 4, nl = c1 & 15;
                    outb[(((size_t)wgi * 1024 + s) * 8 + b) * 64 + gate * 16 + nl] = f2bf(v);
                } else {
                    outf[(size_t)rg * N + cg] = v;
                }
            }
        }
    }
}

// ---------------------------------------------------------------------------
// Persistent LSTM recurrence. 64 WGs x 256 threads. WG wg owns hidden slice
// n in [wg*16, wg*16+16). w_hh B-fragments persistent in registers (bf16).
// h broadcast via MALL (agent-scope write-through stores + sc0/sc1 direct
// loads -> NO L2 invalidates anywhere in the loop). flags polled RELAXED.
__global__ __launch_bounds__(256, 1) void lstm_rec_k(
    const short* __restrict__ xp,    // [64][1024][8][64] bf16  (per-wg slices)
    const float* __restrict__ whh,   // [4096][1024] fp32
    float* __restrict__ h_all,       // [1024][8][1024] fp32
    short* hbuf,                     // [2][16][1024] bf16, pre-zeroed
    unsigned* flags)                 // [1024][64], pre-zeroed
{
    const int wg = blockIdx.x;
    const int tid = threadIdx.x;
    const int lane = tid & 63, wv = tid >> 6;
    __shared__ float scratch[4][64][16];   // [wave][localcol][row]

    // ---- persistent w_hh fragments: wfr[nf][kk], k = wv*256 + kk*32 + (lane>>4)*8 + e
    short8 wfr[4][8];
    {
        const int cl = lane & 15, kq = lane >> 4;
        #pragma unroll
        for (int nf = 0; nf < 4; ++nf){
            int c = nf * 16 + cl;
            int g = (c & 3) * 1024 + wg * 16 + (c >> 2);
            const float* wr = whh + (size_t)g * 1024 + wv * 256 + kq * 8;
            #pragma unroll
            for (int kk = 0; kk < 8; ++kk){
                short8 w;
                #pragma unroll
                for (int e = 0; e < 8; ++e) w[e] = f2bf(wr[kk * 32 + e]);
                wfr[nf][kk] = w;
            }
        }
    }

    const int b_a = tid >> 4, nl_a = tid & 15;   // activation mapping (tid<128)
    float c_reg = 0.f;
    unsigned* hb32 = (unsigned*)hbuf;

    for (int t = 0; t < 1024; ++t){
        // xp prefetch (independent of h); per-wg contiguous 1KB/step
        float xg0 = 0.f, xg1 = 0.f, xg2 = 0.f, xg3 = 0.f;
        if (tid < 128){
            const short* xr = xp + (((size_t)wg * 1024 + t) * 8 + b_a) * 64 + nl_a;
            xg0 = bf2f(xr[0]); xg1 = bf2f(xr[16]); xg2 = bf2f(xr[32]); xg3 = bf2f(xr[48]);
        }
        // all waves poll (RELAXED -> plain MALL load, no L2 invalidate)
        if (t > 0){
            unsigned* fl = flags + (size_t)(t - 1) * 64 + lane;
            int guard = 0;
            while (__hip_atomic_load(fl, __ATOMIC_RELAXED, __HIP_MEMORY_SCOPE_AGENT) == 0u){
                __builtin_amdgcn_s_sleep(1);
                if (++guard > (1 << 18)) break;   // hang insurance
            }
        }

        // ---- h(t-1) fragment loads straight from MALL (bypass L1+L2)
        const short* ha = hbuf + (((t + 1) & 1) * 16 + (lane & 15)) * 1024
                          + wv * 256 + (lane >> 4) * 8;
        short8 af[8];
        #pragma unroll
        for (int kk = 0; kk < 8; ++kk){
            asm volatile("global_load_dwordx4 %0, %1, off sc0 sc1"
                         : "=v"(af[kk]) : "v"(ha + kk * 32) : "memory");
        }
        asm volatile("s_waitcnt vmcnt(0)" ::: "memory");
        __builtin_amdgcn_sched_barrier(0);

        f32x4 a0 = {0.f,0.f,0.f,0.f}, a1 = {0.f,0.f,0.f,0.f};
        f32x4 a2 = {0.f,0.f,0.f,0.f}, a3 = {0.f,0.f,0.f,0.f};
        #pragma unroll
        for (int kk = 0; kk < 8; ++kk){
            a0 = __builtin_amdgcn_mfma_f32_16x16x32_bf16(af[kk], wfr[0][kk], a0, 0, 0, 0);
            a1 = __builtin_amdgcn_mfma_f32_16x16x32_bf16(af[kk], wfr[1][kk], a1, 0, 0, 0);
            a2 = __builtin_amdgcn_mfma_f32_16x16x32_bf16(af[kk], wfr[2][kk], a2, 0, 0, 0);
            a3 = __builtin_amdgcn_mfma_f32_16x16x32_bf16(af[kk], wfr[3][kk], a3, 0, 0, 0);
        }
        {
            int r0 = (lane >> 4) * 4;
            *(f32x4*)&scratch[wv][0 * 16 + (lane & 15)][r0] = a0;
            *(f32x4*)&scratch[wv][1 * 16 + (lane & 15)][r0] = a1;
            *(f32x4*)&scratch[wv][2 * 16 + (lane & 15)][r0] = a2;
            *(f32x4*)&scratch[wv][3 * 16 + (lane & 15)][r0] = a3;
        }
        __syncthreads();

        if (tid < 128){
            int c0 = nl_a * 4;
            float g0 = xg0 + scratch[0][c0+0][b_a] + scratch[1][c0+0][b_a] + scratch[2][c0+0][b_a] + scratch[3][c0+0][b_a];
            float g1 = xg1 + scratch[0][c0+1][b_a] + scratch[1][c0+1][b_a] + scratch[2][c0+1][b_a] + scratch[3][c0+1][b_a];
            float g2 = xg2 + scratch[0][c0+2][b_a] + scratch[1][c0+2][b_a] + scratch[2][c0+2][b_a] + scratch[3][c0+2][b_a];
            float g3 = xg3 + scratch[0][c0+3][b_a] + scratch[1][c0+3][b_a] + scratch[2][c0+3][b_a] + scratch[3][c0+3][b_a];
            float ig = 1.f / (1.f + expf(-g0));
            float fg = 1.f / (1.f + expf(-g1));
            float gg = tanhf(g2);
            float og = 1.f / (1.f + expf(-g3));
            c_reg = fg * c_reg + ig * gg;
            float h = og * tanhf(c_reg);
            h_all[((size_t)t * 8 + b_a) * 1024 + wg * 16 + nl_a] = h;
            unsigned hb = (unsigned)(unsigned short)f2bf(h);
            unsigned oth = (unsigned)__shfl_xor((int)hb, 1);
            if ((tid & 1) == 0){
                unsigned pk = hb | (oth << 16);
                __hip_atomic_store(hb32 + ((size_t)(t & 1) * 16 + b_a) * 512 + wg * 8 + (nl_a >> 1),
                                   pk, __ATOMIC_RELAXED, __HIP_MEMORY_SCOPE_AGENT);
            }
        }
        __syncthreads();   // drains all waves' stores (vmcnt(0) before s_barrier)
        if (tid == 192)    // wave 3 publishes after producers' stores are drained
            __hip_atomic_store(flags + (size_t)t * 64 + wg, 1u,
                               __ATOMIC_RELAXED, __HIP_MEMORY_SCOPE_AGENT);
    }
}

// ---------------------------------------------------------------------------
// span-mean pooling + LayerNorm -> fv (fp32 + bf16)
__global__ __launch_bounds__(256) void pool_ln_k(
    const float* __restrict__ h_all,
    const int* __restrict__ heads, const int* __restrict__ tails,
    const float* __restrict__ lng, const float* __restrict__ lnb,
    float* __restrict__ fv, short* __restrict__ fvb)
{
    const int R = blockIdx.x;           // b*32+j
    const int b = R >> 5;
    const int tid = threadIdx.x;
    __shared__ float red[8];
    int head = heads[R], tail = tails[R];
    float s[4] = {0.f, 0.f, 0.f, 0.f};
    int cnt = 0;
    for (int t = head + 1; t < tail; ++t){
        const float* hp = h_all + ((size_t)t * 8 + b) * 1024;
        #pragma unroll
        for (int i = 0; i < 4; ++i) s[i] += hp[tid + i * 256];
        ++cnt;
    }
    float inv = 1.f / (float)cnt;
    #pragma unroll
    for (int i = 0; i < 4; ++i) s[i] *= inv;
    float mu = blockReduceSum(s[0] + s[1] + s[2] + s[3], red) * (1.f / 1024.f);
    float d2 = 0.f;
    #pragma unroll
    for (int i = 0; i < 4; ++i){ float d = s[i] - mu; d2 += d * d; }
    float var = blockReduceSum(d2, red) * (1.f / 1024.f);
    float rstd = 1.f / sqrtf(var + 1e-7f);
    #pragma unroll
    for (int i = 0; i < 4; ++i){
        int n = tid + i * 256;
        float y = (s[i] - mu) * rstd * lng[n] + lnb[n];
        fv[(size_t)R * 1024 + n] = y;
        fvb[(size_t)R * 1024 + n] = f2bf(y);
    }
}

// ---------------------------------------------------------------------------
// attention per (b, head): qkv [256][3072] fp32 -> ctx_bf16 [256][1024]
__global__ __launch_bounds__(256) void attn_k(
    const float* __restrict__ qkv, const int* __restrict__ amask,
    short* __restrict__ ctxb)
{
    const int b = blockIdx.x >> 4, hh = blockIdx.x & 15;
    const int tid = threadIdx.x;
    __shared__ float q[32][64], k[32][64], v[32][64], sc[32][32];
    #pragma unroll
    for (int i = 0; i < 8; ++i){
        int e = tid + i * 256;
        int j = e >> 6, dd = e & 63;
        const float* base = qkv + (size_t)(b * 32 + j) * 3072 + hh * 64 + dd;
        q[j][dd] = base[0];
        k[j][dd] = base[1024];
        v[j][dd] = base[2048];
    }
    __syncthreads();
    #pragma unroll
    for (int i = 0; i < 4; ++i){
        int e = tid + i * 256;
        int qj = e >> 5, kj = e & 31;
        float d = 0.f;
        #pragma unroll
        for (int x = 0; x < 64; ++x) d += q[qj][x] * k[kj][x];
        bool ok = (amask[b * 32 + qj] * amask[b * 32 + kj]) > 0;
        sc[qj][kj] = ok ? d * 0.125f : -3.402823466e38f;
    }
    __syncthreads();
    if (tid < 32){
        float mx = -3.402823466e38f;
        #pragma unroll
        for (int kj = 0; kj < 32; ++kj) mx = fmaxf(mx, sc[tid][kj]);
        float sum = 0.f;
        #pragma unroll
        for (int kj = 0; kj < 32; ++kj){
            float ev = expf(sc[tid][kj] - mx);
            sc[tid][kj] = ev; sum += ev;
        }
        float inv = 1.f / sum;
        int mq = amask[b * 32 + tid];
        #pragma unroll
        for (int kj = 0; kj < 32; ++kj){
            bool ok = (mq * amask[b * 32 + kj]) > 0;
            sc[tid][kj] = ok ? sc[tid][kj] * inv : 0.f;
        }
    }
    __syncthreads();
    #pragma unroll
    for (int i = 0; i < 8; ++i){
        int e = tid + i * 256;
        int qj = e >> 6, dd = e & 63;
        float s = 0.f;
        #pragma unroll
        for (int kj = 0; kj < 32; ++kj) s += sc[qj][kj] * v[kj][dd];
        ctxb[(size_t)(b * 32 + qj) * 1024 + hh * 64 + dd] = f2bf(s);
    }
}

// ---------------------------------------------------------------------------
// LN2(oproj + fv) then logits = fv2 @ cls_w^T + cls_b  -> d_out[0..768)
__global__ __launch_bounds__(256) void ln2_logits_k(
    const float* __restrict__ oproj, const float* __restrict__ fv,
    const float* __restrict__ g2, const float* __restrict__ b2,
    const float* __restrict__ clsw, const float* __restrict__ clsb,
    float* __restrict__ out)
{
    const int R = blockIdx.x, tid = threadIdx.x;
    __shared__ float red[8];
    float x[4];
    #pragma unroll
    for (int i = 0; i < 4; ++i){
        int n = tid + i * 256;
        x[i] = oproj[(size_t)R * 1024 + n] + fv[(size_t)R * 1024 + n];
    }
    float mu = blockReduceSum(x[0] + x[1] + x[2] + x[3], red) * (1.f / 1024.f);
    float d2 = 0.f;
    #pragma unroll
    for (int i = 0; i < 4; ++i){ float d = x[i] - mu; d2 += d * d; }
    float var = blockReduceSum(d2, red) * (1.f / 1024.f);
    float rstd = 1.f / sqrtf(var + 1e-7f);
    float y[4];
    #pragma unroll
    for (int i = 0; i < 4; ++i){
        int n = tid + i * 256;
        y[i] = (x[i] - mu) * rstd * g2[n] + b2[n];
    }
    #pragma unroll
    for (int c = 0; c < 3; ++c){
        float p = 0.f;
        #pragma unroll
        for (int i = 0; i < 4; ++i){
            int n = tid + i * 256;
            p += y[i] * clsw[c * 1024 + n];
        }
        float tot = blockReduceSum(p, red);
        if (tid == 0) out[R * 3 + c] = tot + clsb[c];
    }
}

// ---------------------------------------------------------------------------
// CE + focal loss over 256 rows of 3 logits -> d_out[768]
__global__ __launch_bounds__(256) void loss_k(
    const float* __restrict__ logits, const int* __restrict__ labels,
    float* __restrict__ out)
{
    const int tid = threadIdx.x;
    __shared__ float red[8];
    float l0 = logits[tid * 3 + 0], l1 = logits[tid * 3 + 1], l2 = logits[tid * 3 + 2];
    int lab = labels[tid];
    float vf = (lab >= 0) ? 1.f : 0.f;
    int lc = lab < 0 ? 0 : (lab > 2 ? 2 : lab);
    float mx = fmaxf(l0, fmaxf(l1, l2));
    float e0 = expf(l0 - mx), e1 = expf(l1 - mx), e2 = expf(l2 - mx);
    float lse = mx + logf(e0 + e1 + e2);
    float lsel = (lc == 0) ? l0 : ((lc == 1) ? l1 : l2);
    float logp = lsel - lse;
    float pt = expf(logp);
    float om = 1.f - pt;
    float nll = -logp;
    float fnll = -(om * om * om * logp);
    float snll = blockReduceSum(nll * vf, red);
    float sfn  = blockReduceSum(fnll * vf, red);
    float svf  = blockReduceSum(vf, red);
    if (tid == 0) out[768] = (snll + sfn) / svf;
}

// ---------------------------------------------------------------------------
extern "C" void kernel_launch(void* const* d_in, const int* in_sizes, int n_in,
                              void* d_out, int out_size, void* d_ws, size_t ws_size,
                              hipStream_t stream)
{
    const float* hidden = (const float*)d_in[0];
    const int*   sh     = (const int*)d_in[1];
    const int*   st     = (const int*)d_in[2];
    const int*   am     = (const int*)d_in[3];
    const int*   labels = (const int*)d_in[4];
    const float* wih    = (const float*)d_in[5];
    const float* whh    = (const float*)d_in[6];
    const float* bih    = (const float*)d_in[7];
    const float* bhh    = (const float*)d_in[8];
    const float* lng    = (const float*)d_in[9];
    const float* lnb    = (const float*)d_in[10];
    const float* wq     = (const float*)d_in[11];
    const float* bq     = (const float*)d_in[12];
    const float* wk     = (const float*)d_in[13];
    const float* bk     = (const float*)d_in[14];
    const float* wvv    = (const float*)d_in[15];
    const float* bv     = (const float*)d_in[16];
    const float* wo     = (const float*)d_in[17];
    const float* bo     = (const float*)d_in[18];
    const float* g2     = (const float*)d_in[19];
    const float* b2     = (const float*)d_in[20];
    const float* clsw   = (const float*)d_in[21];
    const float* clsb   = (const float*)d_in[22];
    float* out = (float*)d_out;

    const size_t MB = 1u << 20;
    const size_t NEED = 136 * MB;
    if (ws_size < NEED){ sentinel_k<<<1, 1, 0, stream>>>(out); return; }

    char* w = (char*)d_ws;
    short*    xp      = (short*)(w);                       // 64MB [64][1024][8][64]
    float*    h_all   = (float*)(w + 64 * MB);             // 32MB [1024][8][1024]
    short*    x_bf    = (short*)(w + 96 * MB);             // 16MB
    short*    wih_bf  = (short*)(w + 112 * MB);            // 8MB
    short*    wqkv_bf = (short*)(w + 120 * MB);            // 6MB
    short*    wo_bf   = (short*)(w + 126 * MB);            // 2MB
    short*    hbuf    = (short*)(w + 128 * MB);            // 64KB
    unsigned* flags   = (unsigned*)(w + 128 * MB + (64u << 10));   // 256KB
    float*    bias_c  = (float*)(w + 128 * MB + (320u << 10));     // 16KB
    float*    bqkv    = (float*)(w + 128 * MB + (336u << 10));     // 12KB
    float*    fv      = (float*)(w + 129 * MB);            // 1MB
    short*    fv_bf   = (short*)(w + 130 * MB);            // 0.5MB
    float*    qkv     = (float*)(w + 131 * MB);            // 3MB
    short*    ctx_bf  = (short*)(w + 134 * MB);            // 0.5MB
    float*    oproj   = (float*)(w + 135 * MB);            // 1MB

    hipMemsetAsync(flags, 0, 1024 * 64 * 4, stream);
    hipMemsetAsync(hbuf, 0, 2 * 16 * 1024 * 2, stream);

    cvt_k<<<8192, 256, 0, stream>>>(hidden, x_bf, 8388608);
    cvt_k<<<4096, 256, 0, stream>>>(wih, wih_bf, 4194304);
    cvt_k<<<1024, 256, 0, stream>>>(wq,  wqkv_bf,           1048576);
    cvt_k<<<1024, 256, 0, stream>>>(wk,  wqkv_bf + 1048576, 1048576);
    cvt_k<<<1024, 256, 0, stream>>>(wvv, wqkv_bf + 2097152, 1048576);
    cvt_k<<<1024, 256, 0, stream>>>(wo,  wo_bf,             1048576);
    prep_small_k<<<16, 256, 0, stream>>>(bih, bhh, bias_c, bq, bk, bv, bqkv);

    // xp = hidden @ w_ih^T + (b_ih + b_hh), stored [wg][t][b][64] bf16
    gemm_bf16_k<<<dim3(32, 64), 256, 0, stream>>>(x_bf, wih_bf, 8192, 4096, 1024,
                                                  bias_c, xp, nullptr, 0);
    // sequential LSTM
    lstm_rec_k<<<64, 256, 0, stream>>>(xp, whh, h_all, hbuf, flags);
    // span-mean pool + LN1
    pool_ln_k<<<256, 256, 0, stream>>>(h_all, sh, st, lng, lnb, fv, fv_bf);
    // q,k,v projections (concat)
    gemm_bf16_k<<<dim3(24, 2), 256, 0, stream>>>(fv_bf, wqkv_bf, 256, 3072, 1024,
                                                 bqkv, nullptr, qkv, 1);
    // attention
    attn_k<<<128, 256, 0, stream>>>(qkv, am, ctx_bf);
    // output projection (+bo)
    gemm_bf16_k<<<dim3(8, 2), 256, 0, stream>>>(ctx_bf, wo_bf, 256, 1024, 1024,
                                                bo, nullptr, oproj, 1);
    // residual + LN2 + classifier logits
    ln2_logits_k<<<256, 256, 0, stream>>>(oproj, fv, g2, b2, clsw, clsb, out);
    // CE + focal loss
    loss_k<<<1, 256, 0, stream>>>(out, labels, out);
}